// Round 6
// baseline (390.569 us; speedup 1.0000x reference)
//
#include <hip/hip_runtime.h>
#include <hip/hip_bf16.h>
#include <math.h>

#define N_TOK 4096
#define D_IN  768
#define N_EXP 8
#define H_DIM 3072
#define NC    6144      // interleaved W1|W2 columns
#define NP    8192      // N_TOK * TOPK
#define BM    128
#define BK    64
#define BN2   128
#define MAXT  72        // 128-row tiles (ffn2)
#define MAXT2 40        // 256-row tiles (ffn1g)
#define GRID1G (MAXT2 * (NC / 256))    // 960, div by 8
#define GRID2  (MAXT * (D_IN / BN2))   // 432, div by 8

typedef float f32x4 __attribute__((ext_vector_type(4)));
typedef short s16x8 __attribute__((ext_vector_type(8)));

__device__ __forceinline__ unsigned short f2bf(float f) {
    unsigned int u = __builtin_bit_cast(unsigned int, f);
    u += 0x7fffu + ((u >> 16) & 1u);
    return (unsigned short)(u >> 16);
}

__device__ __forceinline__ void gload_lds16(const void* g, void* l) {
    __builtin_amdgcn_global_load_lds(
        (const __attribute__((address_space(1))) unsigned int*)g,
        (__attribute__((address_space(3))) unsigned int*)l, 16, 0, 0);
}

__device__ __forceinline__ int xcd_swz(int bid, int nblk) {
    int chunk = nblk >> 3;
    return (bid & 7) * chunk + (bid >> 3);
}

// ---- transpose + f32->bf16 convert, with optional 16-row interleave mapping ----
// mode 0: dst row = ((n>>4)<<5) + (n&15)        (W1 slots)
// mode 1: dst row = ((n>>4)<<5) + 16 + (n&15)   (W2 slots)
// mode 2: dst row = n                            (plain, W3)
__global__ __launch_bounds__(256) void transpose_cvt_kernel(
    const float* __restrict__ src, unsigned short* __restrict__ dst, int R, int C,
    size_t eStride, int mode) {
    __shared__ float t[32][33];
    int e = blockIdx.z;
    int c0 = blockIdx.x * 32, r0 = blockIdx.y * 32;
    int tid = threadIdx.x;
    const float* s = src + (size_t)e * R * C;
    unsigned short* d = dst + (size_t)e * eStride;
    int lc = tid & 31, r4 = tid >> 5;
#pragma unroll
    for (int i = 0; i < 4; i++)
        t[r4 * 4 + i][lc] = s[(size_t)(r0 + r4 * 4 + i) * C + c0 + lc];
    __syncthreads();
    int rq = tid & 7, c = tid >> 3;
    int n = c0 + c;
    int drow = (mode == 2) ? n : (((n >> 4) << 5) + (mode == 1 ? 16 : 0) + (n & 15));
    unsigned long long pk =
          (unsigned long long)f2bf(t[rq * 4 + 0][c])
        | ((unsigned long long)f2bf(t[rq * 4 + 1][c]) << 16)
        | ((unsigned long long)f2bf(t[rq * 4 + 2][c]) << 32)
        | ((unsigned long long)f2bf(t[rq * 4 + 3][c]) << 48);
    *(unsigned long long*)&d[(size_t)drow * R + r0 + rq * 4] = pk;
}

// ---- router ----
__global__ __launch_bounds__(64) void router_kernel(
    const float* __restrict__ x, const float* __restrict__ rw, const float* __restrict__ rb,
    int* counts, int* top1cnt, float* probs_sum, int* tk_e, float* tk_w) {
    __shared__ __align__(16) float s_rw[D_IN * N_EXP];
    __shared__ float s_ps[N_EXP];
    __shared__ int s_cnt[N_EXP], s_t1[N_EXP];
    int tid = threadIdx.x;
    for (int i = tid; i < D_IN * N_EXP / 4; i += 64)
        ((float4*)s_rw)[i] = ((const float4*)rw)[i];
    if (tid < N_EXP) { s_ps[tid] = 0.f; s_cnt[tid] = 0; s_t1[tid] = 0; }
    __syncthreads();

    int tok = blockIdx.x * 64 + tid;
    float acc[N_EXP];
#pragma unroll
    for (int e = 0; e < N_EXP; e++) acc[e] = rb[e];
    const float* xr = x + (size_t)tok * D_IN;
    for (int d = 0; d < D_IN; d++) {
        float xv = xr[d];
#pragma unroll
        for (int e = 0; e < N_EXP; e++) acc[e] += xv * s_rw[d * N_EXP + e];
    }
    float m = acc[0];
#pragma unroll
    for (int e = 1; e < N_EXP; e++) m = fmaxf(m, acc[e]);
    float p[N_EXP], s = 0.f;
#pragma unroll
    for (int e = 0; e < N_EXP; e++) { p[e] = __expf(acc[e] - m); s += p[e]; }
    float inv = 1.f / s;
#pragma unroll
    for (int e = 0; e < N_EXP; e++) p[e] *= inv;
    int e0 = 0;
#pragma unroll
    for (int e = 1; e < N_EXP; e++) if (p[e] > p[e0]) e0 = e;
    int e1 = (e0 == 0) ? 1 : 0;
#pragma unroll
    for (int e = 0; e < N_EXP; e++) if (e != e0 && p[e] > p[e1]) e1 = e;
    float denom = 1.f / (p[e0] + p[e1]);
    tk_e[tok * 2] = e0; tk_e[tok * 2 + 1] = e1;
    tk_w[tok * 2] = p[e0] * denom; tk_w[tok * 2 + 1] = p[e1] * denom;
    atomicAdd(&s_cnt[e0], 1); atomicAdd(&s_cnt[e1], 1); atomicAdd(&s_t1[e0], 1);
#pragma unroll
    for (int e = 0; e < N_EXP; e++) atomicAdd(&s_ps[e], p[e]);
    __syncthreads();
    if (tid < N_EXP) {
        atomicAdd(&counts[tid], s_cnt[tid]);
        atomicAdd(&top1cnt[tid], s_t1[tid]);
        atomicAdd(&probs_sum[tid], s_ps[tid]);
    }
}

// ---- scan: offsets, both tile tables, aux loss ----
__global__ void scan_kernel(const int* counts, const int* top1cnt, const float* probs_sum,
                            int* segOff, int* cursors, int* tileE, int* tileB,
                            int* tileE2, int* tileB2, float* aux_out) {
    if (threadIdx.x == 0 && blockIdx.x == 0) {
        int off = 0, nt = 0, nt2 = 0;
        for (int e = 0; e < N_EXP; e++) {
            segOff[e] = off; cursors[e] = off;
            int c = counts[e]; off += c;
            int t = (c + BM - 1) / BM;
            for (int i = 0; i < t; i++) { tileE[nt] = e; tileB[nt] = i * BM; nt++; }
            int t2 = (c + 255) / 256;
            for (int i = 0; i < t2; i++) { tileE2[nt2] = e; tileB2[nt2] = i * 256; nt2++; }
        }
        segOff[N_EXP] = off;
        for (int i = nt; i < MAXT; i++) { tileE[i] = -1; tileB[i] = 0; }
        for (int i = nt2; i < MAXT2; i++) { tileE2[i] = -1; tileB2[i] = 0; }
        float aux = 0.f;
        for (int e = 0; e < N_EXP; e++) aux += (float)top1cnt[e] * probs_sum[e];
        aux_out[0] = (float)N_EXP * aux / ((float)N_TOK * (float)N_TOK);
    }
}

// ---- scatter ----
__global__ __launch_bounds__(64) void scatter_kernel(
    const int* __restrict__ tk_e, const float* __restrict__ tk_w,
    int* cursors, int* rowTok, float* rowGate, int* pairPos) {
    int tok = blockIdx.x * 64 + threadIdx.x;
#pragma unroll
    for (int k = 0; k < 2; k++) {
        int e = tk_e[tok * 2 + k];
        int pos = atomicAdd(&cursors[e], 1);
        rowTok[pos] = tok;
        rowGate[pos] = tk_w[tok * 2 + k];
        pairPos[tok * 2 + k] = pos;
    }
}

// ---- gather ----
__global__ __launch_bounds__(192) void gather_kernel(
    const float* __restrict__ x, const int* __restrict__ rowTok, unsigned short* __restrict__ Xg) {
    int pos = blockIdx.x;
    int t = rowTok[pos];
    int i = threadIdx.x;
    float4 v = ((const float4*)(x + (size_t)t * D_IN))[i];
    unsigned long long pk = (unsigned long long)f2bf(v.x)
                          | ((unsigned long long)f2bf(v.y) << 16)
                          | ((unsigned long long)f2bf(v.z) << 32)
                          | ((unsigned long long)f2bf(v.w) << 48);
    *(unsigned long long*)(Xg + (size_t)pos * D_IN + (size_t)i * 4) = pk;
}

// ---- ffn1g: Hb = silu(X@W1+b1)*(X@W2+b2) via interleaved Wc, 256x256 8-phase ----
// 512 thr = 8 waves (2m x 4n), wave tile 128x64. LDS 128 KB (2 slots x (A 32K + B 32K)).
// Phases = C-quadrants (mh,nh) x 2 tiles; staging at 64-row units placed at region-death
// points; counted vmcnt(2) at half-iteration boundaries only.
#define PHASE(s, mh, nh, READA, STAGES) do { \
    if (READA) { \
        _Pragma("unroll") \
        for (int ks = 0; ks < 2; ++ks) { \
            _Pragma("unroll") \
            for (int mf = 0; mf < 4; ++mf) { \
                int rr = wm * 128 + (mh) * 64 + mf * 16 + lr; \
                av[ks][mf] = *(const s16x8*)&sA[s][rr * 64 + (((ks * 4 + lh) ^ (rr & 7)) << 3)]; \
            } \
        } \
    } \
    _Pragma("unroll") \
    for (int ks = 0; ks < 2; ++ks) { \
        _Pragma("unroll") \
        for (int nf = 0; nf < 2; ++nf) { \
            int rr = wn * 64 + (nh) * 32 + nf * 16 + lr; \
            bv[ks][nf] = *(const s16x8*)&sB[s][rr * 64 + (((ks * 4 + lh) ^ (rr & 7)) << 3)]; \
        } \
    } \
    STAGES \
    __builtin_amdgcn_sched_barrier(0); \
    __builtin_amdgcn_s_barrier(); \
    asm volatile("s_waitcnt lgkmcnt(0)" ::: "memory"); \
    __builtin_amdgcn_sched_barrier(0); \
    __builtin_amdgcn_s_setprio(1); \
    _Pragma("unroll") \
    for (int ks = 0; ks < 2; ++ks) { \
        _Pragma("unroll") \
        for (int nf = 0; nf < 2; ++nf) { \
            _Pragma("unroll") \
            for (int mf = 0; mf < 4; ++mf) \
                acc[(mh) * 4 + mf][(nh) * 2 + nf] = __builtin_amdgcn_mfma_f32_16x16x32_bf16( \
                    av[ks][mf], bv[ks][nf], acc[(mh) * 4 + mf][(nh) * 2 + nf], 0, 0, 0); \
        } \
    } \
    __builtin_amdgcn_s_setprio(0); \
    __builtin_amdgcn_sched_barrier(0); \
} while (0)

#define BARX __builtin_amdgcn_s_barrier()
#define VMB(n) do { asm volatile("s_waitcnt vmcnt(" #n ")" ::: "memory"); \
                    __builtin_amdgcn_s_barrier(); } while (0)

__global__ __launch_bounds__(512, 2) void ffn1g_kernel(
    const unsigned short* __restrict__ Xg, const unsigned short* __restrict__ Wc,
    const float* __restrict__ b1, const float* __restrict__ b2,
    unsigned short* __restrict__ Hbuf,
    const int* __restrict__ tileE2, const int* __restrict__ tileB2,
    const int* __restrict__ segOff, const int* __restrict__ counts) {
    int u = xcd_swz(blockIdx.x, GRID1G);
    int bx = u / (NC / 256);
    int by = u - bx * (NC / 256);
    int e = tileE2[bx];
    if (e < 0) return;
    int lb = tileB2[bx];
    int g0 = segOff[e] + lb;
    int vr = counts[e] - lb; if (vr > 256) vr = 256;
    int n0 = by * 256;

    __shared__ __align__(16) unsigned short sA[2][256 * 64]; // 64 KB
    __shared__ __align__(16) unsigned short sB[2][256 * 64]; // 64 KB

    int tid = threadIdx.x, lane = tid & 63, w = tid >> 6;
    int wm = w >> 2, wn = w & 3;      // 2m x 4n
    int lr = lane & 15, lh = lane >> 4;

    f32x4 acc[8][4];
#pragma unroll
    for (int a = 0; a < 8; a++)
#pragma unroll
        for (int b = 0; b < 4; b++) acc[a][b] = (f32x4)0.f;

    const unsigned short* We = Wc + (size_t)e * NC * D_IN;

    // stage one 64-row unit (8 KB = 1 load/thread). Linear LDS dest, pre-swizzled source.
    auto stA = [&](int s, int kt, int uq) {
        int o = uq * 8192 + tid * 16;
        int row = o >> 7;
        int cc = ((o >> 4) & 7) ^ (row & 7);
        int gr = g0 + row; if (gr > NP - 1) gr = NP - 1;
        gload_lds16(Xg + (size_t)gr * D_IN + kt * 64 + cc * 8, (char*)&sA[s][0] + o);
    };
    auto stB = [&](int s, int kt, int uq) {
        int o = uq * 8192 + tid * 16;
        int row = o >> 7;
        int cc = ((o >> 4) & 7) ^ (row & 7);
        gload_lds16(We + (size_t)(n0 + row) * D_IN + kt * 64 + cc * 8, (char*)&sB[s][0] + o);
    };

    s16x8 av[2][4], bv[2][2];

    // prologue: tile0 full (8 units) + tile1 A-U0,U2
    stA(0, 0, 0); stA(0, 0, 2); stA(0, 0, 1); stA(0, 0, 3);
    stB(0, 0, 0); stB(0, 0, 1); stB(0, 0, 2); stB(0, 0, 3);
    stA(1, 1, 0); stA(1, 1, 2);
    __builtin_amdgcn_sched_barrier(0);
    VMB(2);

    const int NIT = (D_IN / BK) / 2; // 6
#pragma unroll 1
    for (int i = 0; i < NIT; ++i) {
        int bkt = 2 * i + 1, a2 = 2 * i + 2, bq2 = 2 * i + 3;
        bool more = (i + 1 < NIT);
        PHASE(0, 0, 0, true,  { stA(1, bkt, 1); stA(1, bkt, 3); stB(1, bkt, 0); });
        BARX;
        PHASE(0, 0, 1, false, { stB(1, bkt, 1); stB(1, bkt, 2); stB(1, bkt, 3); });
        BARX;
        PHASE(0, 1, 0, true,  { if (more) { stA(0, a2, 0); stA(0, a2, 2); } });
        BARX;
        PHASE(0, 1, 1, false, {});
        if (more) { VMB(2); } else { VMB(0); }
        PHASE(1, 0, 0, true,  { if (more) { stA(0, a2, 1); stA(0, a2, 3); } });
        BARX;
        PHASE(1, 0, 1, false, { if (more) { stB(0, a2, 0); stB(0, a2, 1); } });
        BARX;
        PHASE(1, 1, 0, true,  { if (more) { stB(0, a2, 2); stB(0, a2, 3); stA(1, bq2, 0); } });
        BARX;
        PHASE(1, 1, 1, false, { if (more) { stA(1, bq2, 2); } });
        VMB(2);
    }

    // epilogue: pair nf-even (W1) with nf-odd (W2), fused bias + silu*mul, bf16 store
    int hbase = ((n0 + wn * 64) >> 5) << 4;
#pragma unroll
    for (int mf8 = 0; mf8 < 8; ++mf8) {
        int rbase = wm * 128 + mf8 * 16 + lh * 4;
#pragma unroll
        for (int p = 0; p < 2; ++p) {
            int hcol = hbase + p * 16 + lr;
            float bb1 = b1[e * H_DIM + hcol], bb2 = b2[e * H_DIM + hcol];
#pragma unroll
            for (int j = 0; j < 4; ++j) {
                int r = rbase + j;
                if (r < vr) {
                    float x1 = acc[mf8][2 * p][j] + bb1;
                    float x2 = acc[mf8][2 * p + 1][j] + bb2;
                    float h = x1 / (1.f + __expf(-x1)) * x2;
                    Hbuf[(size_t)(g0 + r) * H_DIM + hcol] = f2bf(h);
                }
            }
        }
    }
}

// ---- ffn2: Y = gate * (H@W3 + b3), f32 out (R3/R5 structure, measured good) ----
__global__ __launch_bounds__(512) void ffn2_kernel(
    const unsigned short* __restrict__ Hbuf, const unsigned short* __restrict__ W3T,
    const float* __restrict__ b3, const float* __restrict__ rowGate,
    float* __restrict__ Ybuf,
    const int* __restrict__ tileE, const int* __restrict__ tileB,
    const int* __restrict__ segOff, const int* __restrict__ counts) {
    int u = xcd_swz(blockIdx.x, GRID2);
    int bx = u / (D_IN / BN2);
    int by = u - bx * (D_IN / BN2);
    int e = tileE[bx];
    if (e < 0) return;
    int lb = tileB[bx];
    int g0 = segOff[e] + lb;
    int vr = counts[e] - lb; if (vr > BM) vr = BM;
    int n0 = by * BN2;

    __shared__ __align__(16) unsigned short sA[2][BM * BK];
    __shared__ __align__(16) unsigned short sB[2][BN2 * BK];

    int tid = threadIdx.x, lane = tid & 63, w = tid >> 6;
    int wm = w >> 2, wn = w & 3;
    int lr = lane & 15, lh = lane >> 4;

    f32x4 acc[4][2];
#pragma unroll
    for (int a = 0; a < 4; a++)
#pragma unroll
        for (int b = 0; b < 2; b++) acc[a][b] = (f32x4)0.f;

    const unsigned short* W3e = W3T + (size_t)e * D_IN * H_DIM;

    auto stage = [&](int buf, int kt) {
        int kb = kt * BK;
#pragma unroll
        for (int ca = 0; ca < 2; ca++) {
            int o = ca * 8192 + tid * 16;
            int row = o >> 7;
            int c = ((o >> 4) & 7) ^ (row & 7);
            int gr = g0 + row; if (gr > NP - 1) gr = NP - 1;
            gload_lds16(Hbuf + (size_t)gr * H_DIM + kb + c * 8, (char*)&sA[buf][0] + o);
        }
#pragma unroll
        for (int cb = 0; cb < 2; cb++) {
            int o = cb * 8192 + tid * 16;
            int row = o >> 7;
            int c = ((o >> 4) & 7) ^ (row & 7);
            gload_lds16(W3e + (size_t)(n0 + row) * H_DIM + kb + c * 8, (char*)&sB[buf][0] + o);
        }
    };

    const int NKT = H_DIM / BK; // 48
    stage(0, 0);
    stage(1, 1);
    __builtin_amdgcn_sched_barrier(0);
#pragma unroll 1
    for (int kt = 0; kt < NKT; ++kt) {
        if (kt < NKT - 1) { asm volatile("s_waitcnt vmcnt(4)" ::: "memory"); }
        else              { asm volatile("s_waitcnt vmcnt(0)" ::: "memory"); }
        __builtin_amdgcn_s_barrier();
        __builtin_amdgcn_sched_barrier(0);
        int cur = kt & 1;
#pragma unroll
        for (int ks = 0; ks < 2; ++ks) {
            int sb = ks * 4 + lh;
            s16x8 av[4];
#pragma unroll
            for (int mf = 0; mf < 4; ++mf) {
                int r = wm * 64 + mf * 16 + lr;
                av[mf] = *(const s16x8*)&sA[cur][r * 64 + ((sb ^ (r & 7)) << 3)];
            }
#pragma unroll
            for (int nf = 0; nf < 2; ++nf) {
                int n = wn * 32 + nf * 16 + lr;
                s16x8 bvv = *(const s16x8*)&sB[cur][n * 64 + ((sb ^ (n & 7)) << 3)];
#pragma unroll
                for (int mf = 0; mf < 4; ++mf)
                    acc[mf][nf] = __builtin_amdgcn_mfma_f32_16x16x32_bf16(av[mf], bvv, acc[mf][nf], 0, 0, 0);
            }
        }
        __builtin_amdgcn_sched_barrier(0);
        __builtin_amdgcn_s_barrier();
        if (kt + 2 < NKT) { stage(cur, kt + 2); __builtin_amdgcn_sched_barrier(0); }
    }
#pragma unroll
    for (int mf = 0; mf < 4; ++mf) {
        int rbase = wm * 64 + mf * 16 + lh * 4;
#pragma unroll
        for (int nf = 0; nf < 2; ++nf) {
            int n = n0 + wn * 32 + nf * 16 + lr;
            float bb = b3[e * D_IN + n];
#pragma unroll
            for (int j = 0; j < 4; ++j) {
                int r = rbase + j;
                if (r < vr) {
                    float g = rowGate[g0 + r];
                    Ybuf[(size_t)(g0 + r) * D_IN + n] = g * (acc[mf][nf][j] + bb);
                }
            }
        }
    }
}

// ---- combine ----
__global__ __launch_bounds__(192) void combine_kernel(
    const float* __restrict__ Ybuf, const int* __restrict__ pairPos, float* __restrict__ out) {
    int t = blockIdx.x, i = threadIdx.x;
    int p0 = pairPos[t * 2], p1 = pairPos[t * 2 + 1];
    float4 a = ((const float4*)(Ybuf + (size_t)p0 * D_IN))[i];
    float4 b = ((const float4*)(Ybuf + (size_t)p1 * D_IN))[i];
    float4 r; r.x = a.x + b.x; r.y = a.y + b.y; r.z = a.z + b.z; r.w = a.w + b.w;
    ((float4*)(out + (size_t)t * D_IN))[i] = r;
}

extern "C" void kernel_launch(void* const* d_in, const int* in_sizes, int n_in,
                              void* d_out, int out_size, void* d_ws, size_t ws_size,
                              hipStream_t stream) {
    const float* x  = (const float*)d_in[0];
    const float* rw = (const float*)d_in[1];
    const float* rb = (const float*)d_in[2];
    const float* w1 = (const float*)d_in[3];
    const float* b1 = (const float*)d_in[4];
    const float* w2 = (const float*)d_in[5];
    const float* b2 = (const float*)d_in[6];
    const float* w3 = (const float*)d_in[7];
    const float* b3 = (const float*)d_in[8];
    float* out = (float*)d_out;

    char* ws = (char*)d_ws;
    const size_t sWc = (size_t)N_EXP * NC * D_IN * 2;        // 75.5 MB
    const size_t sW3 = (size_t)N_EXP * D_IN * H_DIM * 2;     // 37.7 MB
    const size_t sXg = (size_t)NP * D_IN * 2;                // 12.6 MB
    const size_t sHb = (size_t)NP * H_DIM * 2;               // 50.3 MB
    const size_t sYb = (size_t)NP * D_IN * 4;                // 25.2 MB
    unsigned short* Wc  = (unsigned short*)(ws);
    unsigned short* W3T = (unsigned short*)(ws + sWc);
    unsigned short* Xg  = (unsigned short*)(ws + sWc + sW3);
    unsigned short* Hb  = (unsigned short*)(ws + sWc + sW3 + sXg);
    float* Yb = (float*)(ws + sWc + sW3 + sXg + sHb);
    char* meta = (char*)(ws + sWc + sW3 + sXg + sHb + sYb);
    int*   counts  = (int*)(meta + 0);
    int*   top1    = (int*)(meta + 32);
    float* psum    = (float*)(meta + 64);
    int*   cursors = (int*)(meta + 96);
    int*   segOff  = (int*)(meta + 128);
    int*   tileE   = (int*)(meta + 192);
    int*   tileB   = (int*)(meta + 512);
    int*   tileE2  = (int*)(meta + 1024);
    int*   tileB2  = (int*)(meta + 1280);
    int*   tk_e    = (int*)(meta + 2048);
    float* tk_w    = (float*)(meta + 2048 + 32768);
    int*   rowTok  = (int*)(meta + 2048 + 65536);
    float* rowGate = (float*)(meta + 2048 + 98304);
    int*   pairPos = (int*)(meta + 2048 + 131072);
    size_t need = (size_t)(meta - ws) + 2048 + 131072 + 32768;
    if (ws_size < need) return;

    hipMemsetAsync(meta, 0, 96, stream);
    transpose_cvt_kernel<<<dim3(H_DIM / 32, D_IN / 32, N_EXP), 256, 0, stream>>>(
        w1, Wc, D_IN, H_DIM, (size_t)NC * D_IN, 0);
    transpose_cvt_kernel<<<dim3(H_DIM / 32, D_IN / 32, N_EXP), 256, 0, stream>>>(
        w2, Wc, D_IN, H_DIM, (size_t)NC * D_IN, 1);
    transpose_cvt_kernel<<<dim3(D_IN / 32, H_DIM / 32, N_EXP), 256, 0, stream>>>(
        w3, W3T, H_DIM, D_IN, (size_t)D_IN * H_DIM, 2);
    router_kernel<<<N_TOK / 64, 64, 0, stream>>>(x, rw, rb, counts, top1, psum, tk_e, tk_w);
    scan_kernel<<<1, 64, 0, stream>>>(counts, top1, psum, segOff, cursors, tileE, tileB,
                                      tileE2, tileB2, out + (size_t)N_TOK * D_IN);
    scatter_kernel<<<N_TOK / 64, 64, 0, stream>>>(tk_e, tk_w, cursors, rowTok, rowGate, pairPos);
    gather_kernel<<<NP, 192, 0, stream>>>(x, rowTok, Xg);
    ffn1g_kernel<<<GRID1G, 512, 0, stream>>>(Xg, Wc, b1, b2, Hb,
                                             tileE2, tileB2, segOff, counts);
    ffn2_kernel<<<GRID2, 512, 0, stream>>>(Hb, W3T, b3, rowGate, Yb,
                                           tileE, tileB, segOff, counts);
    combine_kernel<<<N_TOK, 192, 0, stream>>>(Yb, pairPos, out);
}

// Round 7
// 368.520 us; speedup vs baseline: 1.0598x; 1.0598x over previous
//
#include <hip/hip_runtime.h>
#include <hip/hip_bf16.h>
#include <math.h>

#define N_TOK 4096
#define D_IN  768
#define N_EXP 8
#define H_DIM 3072
#define NP    8192      // N_TOK * TOPK
#define BM    128
#define BK    64
#define BN1   64
#define BN2   128
#define MAXT  72        // NP/BM + N_EXP
#define GRID1 (MAXT * (H_DIM / BN1))   // 3456, div by 8
#define GRID2 (MAXT * (D_IN / BN2))    // 432, div by 8

typedef float f32x16 __attribute__((ext_vector_type(16)));
typedef short s16x8 __attribute__((ext_vector_type(8)));

__device__ __forceinline__ unsigned short f2bf(float f) {
    unsigned int u = __builtin_bit_cast(unsigned int, f);
    u += 0x7fffu + ((u >> 16) & 1u);
    return (unsigned short)(u >> 16);
}

__device__ __forceinline__ void gload_lds16(const void* g, void* l) {
    __builtin_amdgcn_global_load_lds(
        (const __attribute__((address_space(1))) unsigned int*)g,
        (__attribute__((address_space(3))) unsigned int*)l, 16, 0, 0);
}

__device__ __forceinline__ int xcd_swz(int bid, int nblk) {
    int chunk = nblk >> 3;
    return (bid & 7) * chunk + (bid >> 3);
}

// ---- transpose + f32->bf16 for W1 and W2 in one launch: z = mat*8 + e ----
__global__ __launch_bounds__(256) void transpose_cvt12_kernel(
    const float* __restrict__ w1, const float* __restrict__ w2,
    unsigned short* __restrict__ W1T, unsigned short* __restrict__ W2T) {
    __shared__ float t[32][33];
    int z = blockIdx.z;
    int e = z & 7;
    const float* s = (z < 8 ? w1 : w2) + (size_t)e * D_IN * H_DIM;
    unsigned short* d = (z < 8 ? W1T : W2T) + (size_t)e * H_DIM * D_IN;
    int c0 = blockIdx.x * 32, r0 = blockIdx.y * 32;
    int tid = threadIdx.x;
    int lc = tid & 31, r4 = tid >> 5;
#pragma unroll
    for (int i = 0; i < 4; i++)
        t[r4 * 4 + i][lc] = s[(size_t)(r0 + r4 * 4 + i) * H_DIM + c0 + lc];
    __syncthreads();
    int rq = tid & 7, c = tid >> 3;
    unsigned long long pk =
          (unsigned long long)f2bf(t[rq * 4 + 0][c])
        | ((unsigned long long)f2bf(t[rq * 4 + 1][c]) << 16)
        | ((unsigned long long)f2bf(t[rq * 4 + 2][c]) << 32)
        | ((unsigned long long)f2bf(t[rq * 4 + 3][c]) << 48);
    *(unsigned long long*)&d[(size_t)(c0 + c) * D_IN + r0 + rq * 4] = pk;
}

// ---- transpose + f32->bf16 for W3: src[e][H][D] -> dst[e][D][H] ----
__global__ __launch_bounds__(256) void transpose_cvt3_kernel(
    const float* __restrict__ src, unsigned short* __restrict__ dst) {
    __shared__ float t[32][33];
    int e = blockIdx.z;
    int c0 = blockIdx.x * 32, r0 = blockIdx.y * 32;
    int tid = threadIdx.x;
    const float* s = src + (size_t)e * H_DIM * D_IN;
    unsigned short* d = dst + (size_t)e * D_IN * H_DIM;
    int lc = tid & 31, r4 = tid >> 5;
#pragma unroll
    for (int i = 0; i < 4; i++)
        t[r4 * 4 + i][lc] = s[(size_t)(r0 + r4 * 4 + i) * D_IN + c0 + lc];
    __syncthreads();
    int rq = tid & 7, c = tid >> 3;
    unsigned long long pk =
          (unsigned long long)f2bf(t[rq * 4 + 0][c])
        | ((unsigned long long)f2bf(t[rq * 4 + 1][c]) << 16)
        | ((unsigned long long)f2bf(t[rq * 4 + 2][c]) << 32)
        | ((unsigned long long)f2bf(t[rq * 4 + 3][c]) << 48);
    *(unsigned long long*)&d[(size_t)(c0 + c) * H_DIM + r0 + rq * 4] = pk;
}

// ---- router ----
__global__ __launch_bounds__(64) void router_kernel(
    const float* __restrict__ x, const float* __restrict__ rw, const float* __restrict__ rb,
    int* counts, int* top1cnt, float* probs_sum, int* tk_e, float* tk_w) {
    __shared__ __align__(16) float s_rw[D_IN * N_EXP];
    __shared__ float s_ps[N_EXP];
    __shared__ int s_cnt[N_EXP], s_t1[N_EXP];
    int tid = threadIdx.x;
    for (int i = tid; i < D_IN * N_EXP / 4; i += 64)
        ((float4*)s_rw)[i] = ((const float4*)rw)[i];
    if (tid < N_EXP) { s_ps[tid] = 0.f; s_cnt[tid] = 0; s_t1[tid] = 0; }
    __syncthreads();

    int tok = blockIdx.x * 64 + tid;
    float acc[N_EXP];
#pragma unroll
    for (int e = 0; e < N_EXP; e++) acc[e] = rb[e];
    const float* xr = x + (size_t)tok * D_IN;
    for (int d = 0; d < D_IN; d++) {
        float xv = xr[d];
#pragma unroll
        for (int e = 0; e < N_EXP; e++) acc[e] += xv * s_rw[d * N_EXP + e];
    }
    float m = acc[0];
#pragma unroll
    for (int e = 1; e < N_EXP; e++) m = fmaxf(m, acc[e]);
    float p[N_EXP], s = 0.f;
#pragma unroll
    for (int e = 0; e < N_EXP; e++) { p[e] = __expf(acc[e] - m); s += p[e]; }
    float inv = 1.f / s;
#pragma unroll
    for (int e = 0; e < N_EXP; e++) p[e] *= inv;
    int e0 = 0;
#pragma unroll
    for (int e = 1; e < N_EXP; e++) if (p[e] > p[e0]) e0 = e;
    int e1 = (e0 == 0) ? 1 : 0;
#pragma unroll
    for (int e = 0; e < N_EXP; e++) if (e != e0 && p[e] > p[e1]) e1 = e;
    float denom = 1.f / (p[e0] + p[e1]);
    tk_e[tok * 2] = e0; tk_e[tok * 2 + 1] = e1;
    tk_w[tok * 2] = p[e0] * denom; tk_w[tok * 2 + 1] = p[e1] * denom;
    atomicAdd(&s_cnt[e0], 1); atomicAdd(&s_cnt[e1], 1); atomicAdd(&s_t1[e0], 1);
#pragma unroll
    for (int e = 0; e < N_EXP; e++) atomicAdd(&s_ps[e], p[e]);
    __syncthreads();
    if (tid < N_EXP) {
        atomicAdd(&counts[tid], s_cnt[tid]);
        atomicAdd(&top1cnt[tid], s_t1[tid]);
        atomicAdd(&probs_sum[tid], s_ps[tid]);
    }
}

// ---- scan ----
__global__ void scan_kernel(const int* counts, const int* top1cnt, const float* probs_sum,
                            int* segOff, int* cursors, int* tileE, int* tileB,
                            float* aux_out) {
    if (threadIdx.x == 0 && blockIdx.x == 0) {
        int off = 0, nt = 0;
        for (int e = 0; e < N_EXP; e++) {
            segOff[e] = off; cursors[e] = off;
            int c = counts[e]; off += c;
            int t = (c + BM - 1) / BM;
            for (int i = 0; i < t; i++) { tileE[nt] = e; tileB[nt] = i * BM; nt++; }
        }
        segOff[N_EXP] = off;
        for (int i = nt; i < MAXT; i++) { tileE[i] = -1; tileB[i] = 0; }
        float aux = 0.f;
        for (int e = 0; e < N_EXP; e++) aux += (float)top1cnt[e] * probs_sum[e];
        aux_out[0] = (float)N_EXP * aux / ((float)N_TOK * (float)N_TOK);
    }
}

// ---- scatter ----
__global__ __launch_bounds__(64) void scatter_kernel(
    const int* __restrict__ tk_e, const float* __restrict__ tk_w,
    int* cursors, int* rowTok, float* rowGate) {
    int tok = blockIdx.x * 64 + threadIdx.x;
#pragma unroll
    for (int k = 0; k < 2; k++) {
        int e = tk_e[tok * 2 + k];
        int pos = atomicAdd(&cursors[e], 1);
        rowTok[pos] = tok;
        rowGate[pos] = tk_w[tok * 2 + k];
    }
}

// ---- gather ----
__global__ __launch_bounds__(192) void gather_kernel(
    const float* __restrict__ x, const int* __restrict__ rowTok, unsigned short* __restrict__ Xg) {
    int pos = blockIdx.x;
    int t = rowTok[pos];
    int i = threadIdx.x;
    float4 v = ((const float4*)(x + (size_t)t * D_IN))[i];
    unsigned long long pk = (unsigned long long)f2bf(v.x)
                          | ((unsigned long long)f2bf(v.y) << 16)
                          | ((unsigned long long)f2bf(v.z) << 32)
                          | ((unsigned long long)f2bf(v.w) << 48);
    *(unsigned long long*)(Xg + (size_t)pos * D_IN + (size_t)i * 4) = pk;
}

// ---- ffn1: H = silu(X@W1+b1) * (X@W2+b2), bf16 out ----
// R5 structure, 32x32x16 MFMA. BM=128 BN1=64 BK=64, 256 thr (4 waves 2m x 2n).
__global__ __launch_bounds__(256) void ffn1_kernel(
    const unsigned short* __restrict__ Xg, const unsigned short* __restrict__ W1T,
    const unsigned short* __restrict__ W2T, const float* __restrict__ b1,
    const float* __restrict__ b2, unsigned short* __restrict__ Hbuf,
    const int* __restrict__ tileE, const int* __restrict__ tileB,
    const int* __restrict__ segOff, const int* __restrict__ counts) {
    int u = xcd_swz(blockIdx.x, GRID1);
    int bx = u / (H_DIM / BN1);
    int by = u - bx * (H_DIM / BN1);
    int e = tileE[bx];
    if (e < 0) return;
    int lb = tileB[bx];
    int g0 = segOff[e] + lb;
    int vr = counts[e] - lb; if (vr > BM) vr = BM;
    int n0 = by * BN1;

    __shared__ __align__(16) unsigned short sA[BM * BK];
    __shared__ __align__(16) unsigned short sB1[BN1 * BK];
    __shared__ __align__(16) unsigned short sB2[BN1 * BK];

    int tid = threadIdx.x, lane = tid & 63, w = tid >> 6;
    int wm = w >> 1, wn = w & 1;
    int l31 = lane & 31, kh = lane >> 5;

    f32x16 acc1[2], acc2[2];
#pragma unroll
    for (int a = 0; a < 2; a++) { acc1[a] = (f32x16)0.f; acc2[a] = (f32x16)0.f; }

    const unsigned short* W1e = W1T + (size_t)e * H_DIM * D_IN;
    const unsigned short* W2e = W2T + (size_t)e * H_DIM * D_IN;

    for (int kt = 0; kt < D_IN / BK; ++kt) {
        int kb = kt * BK;
#pragma unroll
        for (int ra = 0; ra < 4; ra++) {
            int o = ra * 4096 + tid * 16;
            int row = o >> 7;
            int c = ((o >> 4) & 7) ^ (row & 7);
            int gr = g0 + row; if (gr > NP - 1) gr = NP - 1;
            gload_lds16(Xg + (size_t)gr * D_IN + kb + c * 8, (char*)sA + o);
        }
#pragma unroll
        for (int rb2 = 0; rb2 < 2; rb2++) {
            int o = rb2 * 4096 + tid * 16;
            int row = o >> 7;
            int c = ((o >> 4) & 7) ^ (row & 7);
            size_t src = (size_t)(n0 + row) * D_IN + kb + c * 8;
            gload_lds16(W1e + src, (char*)sB1 + o);
            gload_lds16(W2e + src, (char*)sB2 + o);
        }
        asm volatile("s_waitcnt vmcnt(0)" ::: "memory");
        __syncthreads();
#pragma unroll
        for (int ks = 0; ks < 4; ++ks) {
            int ch = ks * 2 + kh;
            int r0r = wm * 64 + l31;
            int r1r = wm * 64 + 32 + l31;
            int nn = wn * 32 + l31;
            s16x8 av0 = *(const s16x8*)&sA[r0r * 64 + ((ch ^ (r0r & 7)) << 3)];
            s16x8 av1 = *(const s16x8*)&sA[r1r * 64 + ((ch ^ (r1r & 7)) << 3)];
            s16x8 bva = *(const s16x8*)&sB1[nn * 64 + ((ch ^ (nn & 7)) << 3)];
            s16x8 bvb = *(const s16x8*)&sB2[nn * 64 + ((ch ^ (nn & 7)) << 3)];
            acc1[0] = __builtin_amdgcn_mfma_f32_32x32x16_bf16(av0, bva, acc1[0], 0, 0, 0);
            acc2[0] = __builtin_amdgcn_mfma_f32_32x32x16_bf16(av0, bvb, acc2[0], 0, 0, 0);
            acc1[1] = __builtin_amdgcn_mfma_f32_32x32x16_bf16(av1, bva, acc1[1], 0, 0, 0);
            acc2[1] = __builtin_amdgcn_mfma_f32_32x32x16_bf16(av1, bvb, acc2[1], 0, 0, 0);
        }
        __syncthreads();
    }
    // epilogue: C/D 32x32 layout col=lane&31, row=(reg&3)+8*(reg>>2)+4*kh
    int n = n0 + wn * 32 + l31;
    float bb1 = b1[e * H_DIM + n], bb2 = b2[e * H_DIM + n];
#pragma unroll
    for (int mf = 0; mf < 2; ++mf) {
#pragma unroll
        for (int reg = 0; reg < 16; ++reg) {
            int r = wm * 64 + mf * 32 + (reg & 3) + 8 * (reg >> 2) + 4 * kh;
            if (r < vr) {
                float x1 = acc1[mf][reg] + bb1;
                float x2 = acc2[mf][reg] + bb2;
                float h = x1 / (1.f + __expf(-x1)) * x2;
                Hbuf[(size_t)(g0 + r) * H_DIM + n] = f2bf(h);
            }
        }
    }
}

// ---- ffn2: out[tok] += gate * (H@W3 + b3) via 2-exact atomics (deterministic) ----
// R5 structure, 32x32x16 MFMA. BM=128 BN2=128 BK=64, 512 thr (8 waves 2m x 4n), counted vmcnt.
__global__ __launch_bounds__(512) void ffn2_kernel(
    const unsigned short* __restrict__ Hbuf, const unsigned short* __restrict__ W3T,
    const float* __restrict__ b3, const float* __restrict__ rowGate,
    const int* __restrict__ rowTok, float* __restrict__ out,
    const int* __restrict__ tileE, const int* __restrict__ tileB,
    const int* __restrict__ segOff, const int* __restrict__ counts) {
    int u = xcd_swz(blockIdx.x, GRID2);
    int bx = u / (D_IN / BN2);
    int by = u - bx * (D_IN / BN2);
    int e = tileE[bx];
    if (e < 0) return;
    int lb = tileB[bx];
    int g0 = segOff[e] + lb;
    int vr = counts[e] - lb; if (vr > BM) vr = BM;
    int n0 = by * BN2;

    __shared__ __align__(16) unsigned short sA[2][BM * BK];
    __shared__ __align__(16) unsigned short sB[2][BN2 * BK];

    int tid = threadIdx.x, lane = tid & 63, w = tid >> 6;
    int wm = w >> 2, wn = w & 3;
    int l31 = lane & 31, kh = lane >> 5;

    f32x16 acc[2];
    acc[0] = (f32x16)0.f; acc[1] = (f32x16)0.f;

    const unsigned short* W3e = W3T + (size_t)e * D_IN * H_DIM;

    auto stage = [&](int buf, int kt) {
        int kb = kt * BK;
#pragma unroll
        for (int ca = 0; ca < 2; ca++) {
            int o = ca * 8192 + tid * 16;
            int row = o >> 7;
            int c = ((o >> 4) & 7) ^ (row & 7);
            int gr = g0 + row; if (gr > NP - 1) gr = NP - 1;
            gload_lds16(Hbuf + (size_t)gr * H_DIM + kb + c * 8, (char*)&sA[buf][0] + o);
        }
#pragma unroll
        for (int cb = 0; cb < 2; cb++) {
            int o = cb * 8192 + tid * 16;
            int row = o >> 7;
            int c = ((o >> 4) & 7) ^ (row & 7);
            gload_lds16(W3e + (size_t)(n0 + row) * H_DIM + kb + c * 8, (char*)&sB[buf][0] + o);
        }
    };

    const int NKT = H_DIM / BK; // 48
    stage(0, 0);
    stage(1, 1);
    __builtin_amdgcn_sched_barrier(0);
#pragma unroll 1
    for (int kt = 0; kt < NKT; ++kt) {
        if (kt < NKT - 1) { asm volatile("s_waitcnt vmcnt(4)" ::: "memory"); }
        else              { asm volatile("s_waitcnt vmcnt(0)" ::: "memory"); }
        __builtin_amdgcn_s_barrier();
        __builtin_amdgcn_sched_barrier(0);
        int cur = kt & 1;
#pragma unroll
        for (int ks = 0; ks < 4; ++ks) {
            int ch = ks * 2 + kh;
            int r0r = wm * 64 + l31;
            int r1r = wm * 64 + 32 + l31;
            int nn = wn * 32 + l31;
            s16x8 av0 = *(const s16x8*)&sA[cur][r0r * 64 + ((ch ^ (r0r & 7)) << 3)];
            s16x8 av1 = *(const s16x8*)&sA[cur][r1r * 64 + ((ch ^ (r1r & 7)) << 3)];
            s16x8 bv = *(const s16x8*)&sB[cur][nn * 64 + ((ch ^ (nn & 7)) << 3)];
            acc[0] = __builtin_amdgcn_mfma_f32_32x32x16_bf16(av0, bv, acc[0], 0, 0, 0);
            acc[1] = __builtin_amdgcn_mfma_f32_32x32x16_bf16(av1, bv, acc[1], 0, 0, 0);
        }
        __builtin_amdgcn_sched_barrier(0);
        __builtin_amdgcn_s_barrier();
        if (kt + 2 < NKT) { stage(cur, kt + 2); __builtin_amdgcn_sched_barrier(0); }
    }
    int n = n0 + wn * 32 + l31;
    float bb = b3[e * D_IN + n];
#pragma unroll
    for (int mf = 0; mf < 2; ++mf) {
#pragma unroll
        for (int reg = 0; reg < 16; ++reg) {
            int r = wm * 64 + mf * 32 + (reg & 3) + 8 * (reg >> 2) + 4 * kh;
            if (r < vr) {
                int g = g0 + r;
                float val = rowGate[g] * (acc[mf][reg] + bb);
                atomicAdd(&out[(size_t)rowTok[g] * D_IN + n], val);
            }
        }
    }
}

extern "C" void kernel_launch(void* const* d_in, const int* in_sizes, int n_in,
                              void* d_out, int out_size, void* d_ws, size_t ws_size,
                              hipStream_t stream) {
    const float* x  = (const float*)d_in[0];
    const float* rw = (const float*)d_in[1];
    const float* rb = (const float*)d_in[2];
    const float* w1 = (const float*)d_in[3];
    const float* b1 = (const float*)d_in[4];
    const float* w2 = (const float*)d_in[5];
    const float* b2 = (const float*)d_in[6];
    const float* w3 = (const float*)d_in[7];
    const float* b3 = (const float*)d_in[8];
    float* out = (float*)d_out;

    char* ws = (char*)d_ws;
    const size_t sW = (size_t)N_EXP * H_DIM * D_IN * 2;
    unsigned short* W1T = (unsigned short*)(ws);
    unsigned short* W2T = (unsigned short*)(ws + sW);
    unsigned short* W3T = (unsigned short*)(ws + 2 * sW);
    unsigned short* Xg  = (unsigned short*)(ws + 3 * sW);
    unsigned short* Hb  = (unsigned short*)(ws + 3 * sW + (size_t)NP * D_IN * 2);
    char* meta = (char*)(Hb + (size_t)NP * H_DIM);
    int*   counts  = (int*)(meta + 0);
    int*   top1    = (int*)(meta + 32);
    float* psum    = (float*)(meta + 64);
    int*   cursors = (int*)(meta + 96);
    int*   segOff  = (int*)(meta + 128);
    int*   tileE   = (int*)(meta + 192);
    int*   tileB   = (int*)(meta + 512);
    int*   tk_e    = (int*)(meta + 1024);
    float* tk_w    = (float*)(meta + 1024 + 32768);
    int*   rowTok  = (int*)(meta + 1024 + 65536);
    float* rowGate = (float*)(meta + 1024 + 98304);
    size_t need = (size_t)(meta - ws) + 1024 + 131072;
    if (ws_size < need) return;

    hipMemsetAsync(meta, 0, 96, stream);
    hipMemsetAsync(out, 0, (size_t)N_TOK * D_IN * sizeof(float), stream);
    transpose_cvt12_kernel<<<dim3(H_DIM / 32, D_IN / 32, 2 * N_EXP), 256, 0, stream>>>(
        w1, w2, W1T, W2T);
    transpose_cvt3_kernel<<<dim3(D_IN / 32, H_DIM / 32, N_EXP), 256, 0, stream>>>(w3, W3T);
    router_kernel<<<N_TOK / 64, 64, 0, stream>>>(x, rw, rb, counts, top1, psum, tk_e, tk_w);
    scan_kernel<<<1, 64, 0, stream>>>(counts, top1, psum, segOff, cursors, tileE, tileB,
                                      out + (size_t)N_TOK * D_IN);
    scatter_kernel<<<N_TOK / 64, 64, 0, stream>>>(tk_e, tk_w, cursors, rowTok, rowGate);
    gather_kernel<<<NP, 192, 0, stream>>>(x, rowTok, Xg);
    ffn1_kernel<<<GRID1, 256, 0, stream>>>(Xg, W1T, W2T, b1, b2, Hb,
                                           tileE, tileB, segOff, counts);
    ffn2_kernel<<<GRID2, 512, 0, stream>>>(Hb, W3T, b3, rowGate, rowTok, out,
                                           tileE, tileB, segOff, counts);
}

// Round 8
// 331.552 us; speedup vs baseline: 1.1780x; 1.1115x over previous
//
#include <hip/hip_runtime.h>
#include <hip/hip_bf16.h>
#include <math.h>

#define N_TOK 4096
#define D_IN  768
#define N_EXP 8
#define H_DIM 3072
#define NP    8192      // N_TOK * TOPK
#define BM    128
#define BK    64
#define BN1   128
#define BN2   128
#define MAXT  72        // max 128-row tiles
#define GRID1 (MAXT * (H_DIM / BN1))   // 1728, div by 8
#define GRID2 (MAXT * (D_IN / BN2))    // 432, div by 8

typedef float f32x4 __attribute__((ext_vector_type(4)));
typedef short s16x8 __attribute__((ext_vector_type(8)));

__device__ __forceinline__ unsigned short f2bf(float f) {
    unsigned int u = __builtin_bit_cast(unsigned int, f);
    u += 0x7fffu + ((u >> 16) & 1u);
    return (unsigned short)(u >> 16);
}

__device__ __forceinline__ void gload_lds16(const void* g, void* l) {
    __builtin_amdgcn_global_load_lds(
        (const __attribute__((address_space(1))) unsigned int*)g,
        (__attribute__((address_space(3))) unsigned int*)l, 16, 0, 0);
}

__device__ __forceinline__ int xcd_swz(int bid, int nblk) {
    int chunk = nblk >> 3;
    return (bid & 7) * chunk + (bid >> 3);
}

// tile map from counts: block bx -> (e, lb, g0, vr) for 128-row tiles
__device__ __forceinline__ bool tile_map(const int* counts, int bx, int& e, int& g0, int& vr) {
    int off = 0, nt = 0;
    e = -1;
    int lb = 0, cnt = 0;
#pragma unroll
    for (int ee = 0; ee < N_EXP; ee++) {
        int c = counts[ee];
        int t = (c + BM - 1) >> 7;
        if (bx >= nt && bx < nt + t) { e = ee; lb = (bx - nt) * BM; g0 = off + lb; cnt = c; }
        nt += t; off += c;
    }
    if (e < 0) return false;
    vr = cnt - lb; if (vr > BM) vr = BM;
    return true;
}

// ---- prep: all 3 weight transposes (f32->bf16) + router, one launch ----
// blocks [0, 36864): w1/w2 transpose; [36864, 55296): w3; [55296, 55360): router
#define NTB 2304   // (3072/32)*(768/32)
__global__ __launch_bounds__(256) void prep_kernel(
    const float* __restrict__ w1, const float* __restrict__ w2, const float* __restrict__ w3,
    unsigned short* __restrict__ W1T, unsigned short* __restrict__ W2T,
    unsigned short* __restrict__ W3T,
    const float* __restrict__ x, const float* __restrict__ rw, const float* __restrict__ rb,
    int* counts, int* top1cnt, float* probs_sum, int* tk_e, float* tk_w) {
    __shared__ float t[32][33];
    __shared__ __align__(16) float s_rw[D_IN * N_EXP];
    __shared__ float s_ps[N_EXP];
    __shared__ int s_cnt[N_EXP], s_t1[N_EXP];
    int bid = blockIdx.x, tid = threadIdx.x;

    if (bid < 16 * NTB) {             // w1/w2: src [768][3072] -> dst [3072][768]
        int z = bid / NTB;            // 0..15
        int e = z & 7;
        const float* s = (z < 8 ? w1 : w2) + (size_t)e * D_IN * H_DIM;
        unsigned short* d = (z < 8 ? W1T : W2T) + (size_t)e * H_DIM * D_IN;
        int tt = bid - z * NTB;
        int c0 = (tt % 96) * 32, r0 = (tt / 96) * 32;
        int lc = tid & 31, r4 = tid >> 5;
#pragma unroll
        for (int i = 0; i < 4; i++)
            t[r4 * 4 + i][lc] = s[(size_t)(r0 + r4 * 4 + i) * H_DIM + c0 + lc];
        __syncthreads();
        int rq = tid & 7, c = tid >> 3;
        unsigned long long pk =
              (unsigned long long)f2bf(t[rq * 4 + 0][c])
            | ((unsigned long long)f2bf(t[rq * 4 + 1][c]) << 16)
            | ((unsigned long long)f2bf(t[rq * 4 + 2][c]) << 32)
            | ((unsigned long long)f2bf(t[rq * 4 + 3][c]) << 48);
        *(unsigned long long*)&d[(size_t)(c0 + c) * D_IN + r0 + rq * 4] = pk;
    } else if (bid < 24 * NTB) {      // w3: src [3072][768] -> dst [768][3072]
        int z = bid / NTB - 16;       // e
        const float* s = w3 + (size_t)z * H_DIM * D_IN;
        unsigned short* d = W3T + (size_t)z * D_IN * H_DIM;
        int tt = bid - (z + 16) * NTB;
        int c0 = (tt % 24) * 32, r0 = (tt / 24) * 32;
        int lc = tid & 31, r4 = tid >> 5;
#pragma unroll
        for (int i = 0; i < 4; i++)
            t[r4 * 4 + i][lc] = s[(size_t)(r0 + r4 * 4 + i) * D_IN + c0 + lc];
        __syncthreads();
        int rq = tid & 7, c = tid >> 3;
        unsigned long long pk =
              (unsigned long long)f2bf(t[rq * 4 + 0][c])
            | ((unsigned long long)f2bf(t[rq * 4 + 1][c]) << 16)
            | ((unsigned long long)f2bf(t[rq * 4 + 2][c]) << 32)
            | ((unsigned long long)f2bf(t[rq * 4 + 3][c]) << 48);
        *(unsigned long long*)&d[(size_t)(c0 + c) * H_DIM + r0 + rq * 4] = pk;
    } else {                          // router: 64 blocks x 64 tokens
        int rbid = bid - 24 * NTB;
        for (int i = tid; i < D_IN * N_EXP / 4; i += 256)
            ((float4*)s_rw)[i] = ((const float4*)rw)[i];
        if (tid < N_EXP) { s_ps[tid] = 0.f; s_cnt[tid] = 0; s_t1[tid] = 0; }
        __syncthreads();
        if (tid < 64) {
            int tok = rbid * 64 + tid;
            float acc[N_EXP];
#pragma unroll
            for (int e = 0; e < N_EXP; e++) acc[e] = rb[e];
            const float* xr = x + (size_t)tok * D_IN;
            for (int d = 0; d < D_IN; d++) {
                float xv = xr[d];
#pragma unroll
                for (int e = 0; e < N_EXP; e++) acc[e] += xv * s_rw[d * N_EXP + e];
            }
            float m = acc[0];
#pragma unroll
            for (int e = 1; e < N_EXP; e++) m = fmaxf(m, acc[e]);
            float p[N_EXP], s = 0.f;
#pragma unroll
            for (int e = 0; e < N_EXP; e++) { p[e] = __expf(acc[e] - m); s += p[e]; }
            float inv = 1.f / s;
#pragma unroll
            for (int e = 0; e < N_EXP; e++) p[e] *= inv;
            int e0 = 0;
#pragma unroll
            for (int e = 1; e < N_EXP; e++) if (p[e] > p[e0]) e0 = e;
            int e1 = (e0 == 0) ? 1 : 0;
#pragma unroll
            for (int e = 0; e < N_EXP; e++) if (e != e0 && p[e] > p[e1]) e1 = e;
            float denom = 1.f / (p[e0] + p[e1]);
            tk_e[tok * 2] = e0; tk_e[tok * 2 + 1] = e1;
            tk_w[tok * 2] = p[e0] * denom; tk_w[tok * 2 + 1] = p[e1] * denom;
            atomicAdd(&s_cnt[e0], 1); atomicAdd(&s_cnt[e1], 1); atomicAdd(&s_t1[e0], 1);
#pragma unroll
            for (int e = 0; e < N_EXP; e++) atomicAdd(&s_ps[e], p[e]);
        }
        __syncthreads();
        if (tid < N_EXP) {
            atomicAdd(&counts[tid], s_cnt[tid]);
            atomicAdd(&top1cnt[tid], s_t1[tid]);
            atomicAdd(&probs_sum[tid], s_ps[tid]);
        }
    }
}

// ---- scatter: permutation via inline prefix of counts; block0 computes aux ----
__global__ __launch_bounds__(64) void scatter_kernel(
    const int* __restrict__ tk_e, const float* __restrict__ tk_w,
    const int* __restrict__ counts, int* cursors,
    int* rowTok, float* rowGate, int* pairPos,
    const int* __restrict__ top1cnt, const float* __restrict__ probs_sum, float* aux_out) {
    int tid = threadIdx.x;
    int tok = blockIdx.x * 64 + tid;
    int segOff[N_EXP];
    int off = 0;
#pragma unroll
    for (int e = 0; e < N_EXP; e++) { segOff[e] = off; off += counts[e]; }
#pragma unroll
    for (int k = 0; k < 2; k++) {
        int e = tk_e[tok * 2 + k];
        int pos = segOff[e] + atomicAdd(&cursors[e], 1);
        rowTok[pos] = tok;
        rowGate[pos] = tk_w[tok * 2 + k];
        pairPos[tok * 2 + k] = pos;
    }
    if (blockIdx.x == 0 && tid == 0) {
        float aux = 0.f;
#pragma unroll
        for (int e = 0; e < N_EXP; e++) aux += (float)top1cnt[e] * probs_sum[e];
        aux_out[0] = (float)N_EXP * aux / ((float)N_TOK * (float)N_TOK);
    }
}

// ---- gather ----
__global__ __launch_bounds__(192) void gather_kernel(
    const float* __restrict__ x, const int* __restrict__ rowTok, unsigned short* __restrict__ Xg) {
    int pos = blockIdx.x;
    int t = rowTok[pos];
    int i = threadIdx.x;
    float4 v = ((const float4*)(x + (size_t)t * D_IN))[i];
    unsigned long long pk = (unsigned long long)f2bf(v.x)
                          | ((unsigned long long)f2bf(v.y) << 16)
                          | ((unsigned long long)f2bf(v.z) << 32)
                          | ((unsigned long long)f2bf(v.w) << 48);
    *(unsigned long long*)(Xg + (size_t)pos * D_IN + (size_t)i * 4) = pk;
}

// ---- ffn1: H = silu(X@W1+b1) * (X@W2+b2), bf16 out ----
// 512 thr, 8 waves (2m x 4n), wave tile 64x32 dual, BM=128 BN1=128 BK=64, 48 KB LDS, 2ph.
__global__ __launch_bounds__(512) void ffn1_kernel(
    const unsigned short* __restrict__ Xg, const unsigned short* __restrict__ W1T,
    const unsigned short* __restrict__ W2T, const float* __restrict__ b1,
    const float* __restrict__ b2, unsigned short* __restrict__ Hbuf,
    const int* __restrict__ counts) {
    int u = xcd_swz(blockIdx.x, GRID1);
    int bx = u / (H_DIM / BN1);
    int by = u - bx * (H_DIM / BN1);
    int e, g0, vr;
    if (!tile_map(counts, bx, e, g0, vr)) return;
    int n0 = by * BN1;

    __shared__ __align__(16) unsigned short sA[BM * BK];    // 16 KB
    __shared__ __align__(16) unsigned short sB1[BN1 * BK];  // 16 KB
    __shared__ __align__(16) unsigned short sB2[BN1 * BK];  // 16 KB

    int tid = threadIdx.x, lane = tid & 63, w = tid >> 6;
    int wm = w >> 2, wn = w & 3;
    int lr = lane & 15, lh = lane >> 4;

    f32x4 acc1[4][2], acc2[4][2];
#pragma unroll
    for (int a = 0; a < 4; a++)
#pragma unroll
        for (int b = 0; b < 2; b++) { acc1[a][b] = (f32x4)0.f; acc2[a][b] = (f32x4)0.f; }

    const unsigned short* W1e = W1T + (size_t)e * H_DIM * D_IN;
    const unsigned short* W2e = W2T + (size_t)e * H_DIM * D_IN;

    for (int kt = 0; kt < D_IN / BK; ++kt) {
        int kb = kt * BK;
#pragma unroll
        for (int ra = 0; ra < 2; ra++) {
            int o = ra * 8192 + tid * 16;
            int row = o >> 7;
            int c = ((o >> 4) & 7) ^ (row & 7);
            int gr = g0 + row; if (gr > NP - 1) gr = NP - 1;
            gload_lds16(Xg + (size_t)gr * D_IN + kb + c * 8, (char*)sA + o);
        }
#pragma unroll
        for (int rb2 = 0; rb2 < 2; rb2++) {
            int o = rb2 * 8192 + tid * 16;
            int row = o >> 7;
            int c = ((o >> 4) & 7) ^ (row & 7);
            size_t src = (size_t)(n0 + row) * D_IN + kb + c * 8;
            gload_lds16(W1e + src, (char*)sB1 + o);
            gload_lds16(W2e + src, (char*)sB2 + o);
        }
        asm volatile("s_waitcnt vmcnt(0)" ::: "memory");
        __syncthreads();
#pragma unroll
        for (int ks = 0; ks < 2; ++ks) {
            int sb = ks * 4 + lh;
            s16x8 av[4];
#pragma unroll
            for (int mf = 0; mf < 4; ++mf) {
                int r = wm * 64 + mf * 16 + lr;
                av[mf] = *(const s16x8*)&sA[r * 64 + ((sb ^ (r & 7)) << 3)];
            }
#pragma unroll
            for (int nf = 0; nf < 2; ++nf) {
                int n = wn * 32 + nf * 16 + lr;
                int off = n * 64 + ((sb ^ (n & 7)) << 3);
                s16x8 bv1 = *(const s16x8*)&sB1[off];
                s16x8 bv2 = *(const s16x8*)&sB2[off];
#pragma unroll
                for (int mf = 0; mf < 4; ++mf) {
                    acc1[mf][nf] = __builtin_amdgcn_mfma_f32_16x16x32_bf16(av[mf], bv1, acc1[mf][nf], 0, 0, 0);
                    acc2[mf][nf] = __builtin_amdgcn_mfma_f32_16x16x32_bf16(av[mf], bv2, acc2[mf][nf], 0, 0, 0);
                }
            }
        }
        __syncthreads();
    }
#pragma unroll
    for (int mf = 0; mf < 4; ++mf) {
        int rbase = wm * 64 + mf * 16 + lh * 4;
#pragma unroll
        for (int nf = 0; nf < 2; ++nf) {
            int n = n0 + wn * 32 + nf * 16 + lr;
            float bb1 = b1[e * H_DIM + n], bb2 = b2[e * H_DIM + n];
#pragma unroll
            for (int j = 0; j < 4; ++j) {
                int r = rbase + j;
                if (r < vr) {
                    float x1 = acc1[mf][nf][j] + bb1;
                    float x2 = acc2[mf][nf][j] + bb2;
                    float h = x1 / (1.f + __expf(-x1)) * x2;
                    Hbuf[(size_t)(g0 + r) * H_DIM + n] = f2bf(h);
                }
            }
        }
    }
}

// ---- ffn2: Y = gate * (H@W3 + b3), f32 out ----
// 256 thr, 4 waves (2m x 2n), wave tile 64x64, BM=128 BN2=128 BK=64, counted-vmcnt dbuf.
__global__ __launch_bounds__(256) void ffn2_kernel(
    const unsigned short* __restrict__ Hbuf, const unsigned short* __restrict__ W3T,
    const float* __restrict__ b3, const float* __restrict__ rowGate,
    float* __restrict__ Ybuf, const int* __restrict__ counts) {
    int u = xcd_swz(blockIdx.x, GRID2);
    int bx = u / (D_IN / BN2);
    int by = u - bx * (D_IN / BN2);
    int e, g0, vr;
    if (!tile_map(counts, bx, e, g0, vr)) return;
    int n0 = by * BN2;

    __shared__ __align__(16) unsigned short sA[2][BM * BK];   // 32 KB
    __shared__ __align__(16) unsigned short sB[2][BN2 * BK];  // 32 KB

    int tid = threadIdx.x, lane = tid & 63, w = tid >> 6;
    int wm = w >> 1, wn = w & 1;     // 2m x 2n, wave tile 64 x 64
    int lr = lane & 15, lh = lane >> 4;

    f32x4 acc[4][4];
#pragma unroll
    for (int a = 0; a < 4; a++)
#pragma unroll
        for (int b = 0; b < 4; b++) acc[a][b] = (f32x4)0.f;

    const unsigned short* W3e = W3T + (size_t)e * D_IN * H_DIM;

    auto stage = [&](int buf, int kt) {
        int kb = kt * BK;
#pragma unroll
        for (int ca = 0; ca < 4; ca++) {
            int o = ca * 4096 + tid * 16;
            int row = o >> 7;
            int c = ((o >> 4) & 7) ^ (row & 7);
            int gr = g0 + row; if (gr > NP - 1) gr = NP - 1;
            gload_lds16(Hbuf + (size_t)gr * H_DIM + kb + c * 8, (char*)&sA[buf][0] + o);
        }
#pragma unroll
        for (int cb = 0; cb < 4; cb++) {
            int o = cb * 4096 + tid * 16;
            int row = o >> 7;
            int c = ((o >> 4) & 7) ^ (row & 7);
            gload_lds16(W3e + (size_t)(n0 + row) * H_DIM + kb + c * 8, (char*)&sB[buf][0] + o);
        }
    };

    const int NKT = H_DIM / BK; // 48
    stage(0, 0);
    stage(1, 1);
    __builtin_amdgcn_sched_barrier(0);
#pragma unroll 1
    for (int kt = 0; kt < NKT; ++kt) {
        if (kt < NKT - 1) { asm volatile("s_waitcnt vmcnt(8)" ::: "memory"); }
        else              { asm volatile("s_waitcnt vmcnt(0)" ::: "memory"); }
        __builtin_amdgcn_s_barrier();
        __builtin_amdgcn_sched_barrier(0);
        int cur = kt & 1;
#pragma unroll
        for (int ks = 0; ks < 2; ++ks) {
            int sb = ks * 4 + lh;
            s16x8 av[4], bv[4];
#pragma unroll
            for (int mf = 0; mf < 4; ++mf) {
                int r = wm * 64 + mf * 16 + lr;
                av[mf] = *(const s16x8*)&sA[cur][r * 64 + ((sb ^ (r & 7)) << 3)];
            }
#pragma unroll
            for (int nf = 0; nf < 4; ++nf) {
                int n = wn * 64 + nf * 16 + lr;
                bv[nf] = *(const s16x8*)&sB[cur][n * 64 + ((sb ^ (n & 7)) << 3)];
            }
#pragma unroll
            for (int nf = 0; nf < 4; ++nf)
#pragma unroll
                for (int mf = 0; mf < 4; ++mf)
                    acc[mf][nf] = __builtin_amdgcn_mfma_f32_16x16x32_bf16(av[mf], bv[nf], acc[mf][nf], 0, 0, 0);
        }
        __builtin_amdgcn_sched_barrier(0);
        __builtin_amdgcn_s_barrier();
        if (kt + 2 < NKT) { stage(cur, kt + 2); __builtin_amdgcn_sched_barrier(0); }
    }
#pragma unroll
    for (int mf = 0; mf < 4; ++mf) {
        int rbase = wm * 64 + mf * 16 + lh * 4;
#pragma unroll
        for (int nf = 0; nf < 4; ++nf) {
            int n = n0 + wn * 64 + nf * 16 + lr;
            float bb = b3[e * D_IN + n];
#pragma unroll
            for (int j = 0; j < 4; ++j) {
                int r = rbase + j;
                if (r < vr) {
                    float g = rowGate[g0 + r];
                    Ybuf[(size_t)(g0 + r) * D_IN + n] = g * (acc[mf][nf][j] + bb);
                }
            }
        }
    }
}

// ---- combine ----
__global__ __launch_bounds__(192) void combine_kernel(
    const float* __restrict__ Ybuf, const int* __restrict__ pairPos, float* __restrict__ out) {
    int t = blockIdx.x, i = threadIdx.x;
    int p0 = pairPos[t * 2], p1 = pairPos[t * 2 + 1];
    float4 a = ((const float4*)(Ybuf + (size_t)p0 * D_IN))[i];
    float4 b = ((const float4*)(Ybuf + (size_t)p1 * D_IN))[i];
    float4 r; r.x = a.x + b.x; r.y = a.y + b.y; r.z = a.z + b.z; r.w = a.w + b.w;
    ((float4*)(out + (size_t)t * D_IN))[i] = r;
}

extern "C" void kernel_launch(void* const* d_in, const int* in_sizes, int n_in,
                              void* d_out, int out_size, void* d_ws, size_t ws_size,
                              hipStream_t stream) {
    const float* x  = (const float*)d_in[0];
    const float* rw = (const float*)d_in[1];
    const float* rb = (const float*)d_in[2];
    const float* w1 = (const float*)d_in[3];
    const float* b1 = (const float*)d_in[4];
    const float* w2 = (const float*)d_in[5];
    const float* b2 = (const float*)d_in[6];
    const float* w3 = (const float*)d_in[7];
    const float* b3 = (const float*)d_in[8];
    float* out = (float*)d_out;

    char* ws = (char*)d_ws;
    const size_t sW = (size_t)N_EXP * H_DIM * D_IN * 2;
    unsigned short* W1T = (unsigned short*)(ws);
    unsigned short* W2T = (unsigned short*)(ws + sW);
    unsigned short* W3T = (unsigned short*)(ws + 2 * sW);
    unsigned short* Xg  = (unsigned short*)(ws + 3 * sW);
    unsigned short* Hb  = (unsigned short*)(ws + 3 * sW + (size_t)NP * D_IN * 2);
    float* Yb = (float*)(ws + 3 * sW + (size_t)NP * D_IN * 2 + (size_t)NP * H_DIM * 2);
    char* meta = (char*)(Yb + (size_t)NP * D_IN);
    int*   counts  = (int*)(meta + 0);
    int*   top1    = (int*)(meta + 32);
    float* psum    = (float*)(meta + 64);
    int*   cursors = (int*)(meta + 96);
    int*   tk_e    = (int*)(meta + 1024);
    float* tk_w    = (float*)(meta + 1024 + 32768);
    int*   rowTok  = (int*)(meta + 1024 + 65536);
    float* rowGate = (float*)(meta + 1024 + 98304);
    int*   pairPos = (int*)(meta + 1024 + 131072);
    size_t need = (size_t)(meta - ws) + 1024 + 163840;
    if (ws_size < need) return;

    hipMemsetAsync(meta, 0, 128, stream);
    prep_kernel<<<24 * NTB + 64, 256, 0, stream>>>(
        w1, w2, w3, W1T, W2T, W3T, x, rw, rb, counts, top1, psum, tk_e, tk_w);
    scatter_kernel<<<N_TOK / 64, 64, 0, stream>>>(
        tk_e, tk_w, counts, cursors, rowTok, rowGate, pairPos,
        top1, psum, out + (size_t)N_TOK * D_IN);
    gather_kernel<<<NP, 192, 0, stream>>>(x, rowTok, Xg);
    ffn1_kernel<<<GRID1, 512, 0, stream>>>(Xg, W1T, W2T, b1, b2, Hb, counts);
    ffn2_kernel<<<GRID2, 256, 0, stream>>>(Hb, W3T, b3, rowGate, Yb, counts);
    combine_kernel<<<N_TOK, 192, 0, stream>>>(Yb, pairPos, out);
}

// Round 9
// 322.886 us; speedup vs baseline: 1.2096x; 1.0268x over previous
//
#include <hip/hip_runtime.h>
#include <hip/hip_bf16.h>
#include <math.h>

#define N_TOK 4096
#define D_IN  768
#define N_EXP 8
#define NP    8192      // N_TOK * TOPK
#define H_DIM 3072
#define BM    128
#define BK    64
#define BN1   128
#define BN2   128
#define MAXT  72
#define GRID1 (MAXT * (H_DIM / BN1))   // 1728, div by 8
#define GRID2 (MAXT * (D_IN / BN2))    // 432, div by 8
#define NT_BLKS 6912                   // 24 mats * 288 tiles
#define TPE   288                      // tiles per (matrix, expert)

typedef float f32x4 __attribute__((ext_vector_type(4)));
typedef short s16x8 __attribute__((ext_vector_type(8)));

__device__ __forceinline__ unsigned short f2bf(float f) {
    unsigned int u = __builtin_bit_cast(unsigned int, f);
    u += 0x7fffu + ((u >> 16) & 1u);
    return (unsigned short)(u >> 16);
}

__device__ __forceinline__ void gload_lds16(const void* g, void* l) {
    __builtin_amdgcn_global_load_lds(
        (const __attribute__((address_space(1))) unsigned int*)g,
        (__attribute__((address_space(3))) unsigned int*)l, 16, 0, 0);
}

__device__ __forceinline__ int xcd_swz(int bid, int nblk) {
    int chunk = nblk >> 3;
    return (bid & 7) * chunk + (bid >> 3);
}

__device__ __forceinline__ bool tile_map(const int* counts, int bx, int& e, int& g0, int& vr) {
    int off = 0, nt = 0;
    e = -1;
    int lb = 0, cnt = 0;
#pragma unroll
    for (int ee = 0; ee < N_EXP; ee++) {
        int c = counts[ee];
        int t = (c + BM - 1) >> 7;
        if (bx >= nt && bx < nt + t) { e = ee; lb = (bx - nt) * BM; g0 = off + lb; cnt = c; }
        nt += t; off += c;
    }
    if (e < 0) return false;
    vr = cnt - lb; if (vr > BM) vr = BM;
    return true;
}

// ---- prep: register-only weight transposes (64x128 src tiles) + router ----
// blocks [0, 6912): transposes; [6912, 6976): router (64 blocks x 64 tokens)
__global__ __launch_bounds__(256) void prep_kernel(
    const float* __restrict__ w1, const float* __restrict__ w2, const float* __restrict__ w3,
    unsigned short* __restrict__ W1T, unsigned short* __restrict__ W2T,
    unsigned short* __restrict__ W3T,
    const float* __restrict__ x, const float* __restrict__ rw, const float* __restrict__ rb,
    int* counts, int* top1cnt, float* probs_sum, int* tk_e, float* tk_w) {
    int bid = blockIdx.x, tid = threadIdx.x;

    if (bid < NT_BLKS) {
        // pick matrix/expert: z 0..7 -> w1, 8..15 -> w2, 16..23 -> w3
        int z = bid / TPE;
        int tt = bid - z * TPE;
        const float* s;
        unsigned short* d;
        int R, C, tc;
        if (z < 8)       { s = w1 + (size_t)z * D_IN * H_DIM;        d = W1T + (size_t)z * H_DIM * D_IN;        R = D_IN;  C = H_DIM; tc = 24; }
        else if (z < 16) { s = w2 + (size_t)(z - 8) * D_IN * H_DIM;  d = W2T + (size_t)(z - 8) * H_DIM * D_IN;  R = D_IN;  C = H_DIM; tc = 24; }
        else             { s = w3 + (size_t)(z - 16) * H_DIM * D_IN; d = W3T + (size_t)(z - 16) * D_IN * H_DIM; R = H_DIM; C = D_IN;  tc = 6;  }
        int r0 = (tt / tc) * 64, c0 = (tt % tc) * 128;
        int lane = tid & 63, w = tid >> 6;
        int tx = lane & 7, ty = lane >> 3;
        int cb = c0 + 32 * w + 4 * tx;      // 4-col group this thread owns
        int rb2 = r0 + 8 * ty;              // 8-row group
        const float* sp = s + (size_t)rb2 * C + cb;
        f32x4 L[8];
#pragma unroll
        for (int i = 0; i < 8; i++)
            L[i] = *(const f32x4*)(sp + (size_t)i * C);
#pragma unroll
        for (int j = 0; j < 4; j++) {
            s16x8 o;
#pragma unroll
            for (int k = 0; k < 8; k++) o[k] = (short)f2bf(L[k][j]);
            *(s16x8*)&d[(size_t)(cb + j) * R + rb2] = o;
        }
    } else {
        __shared__ __align__(16) float s_rw[D_IN * N_EXP];
        __shared__ float s_ps[N_EXP];
        __shared__ int s_cnt[N_EXP], s_t1[N_EXP];
        int rbid = bid - NT_BLKS;
        for (int i = tid; i < D_IN * N_EXP / 4; i += 256)
            ((float4*)s_rw)[i] = ((const float4*)rw)[i];
        if (tid < N_EXP) { s_ps[tid] = 0.f; s_cnt[tid] = 0; s_t1[tid] = 0; }
        __syncthreads();
        if (tid < 64) {
            int tok = rbid * 64 + tid;
            float acc[N_EXP];
#pragma unroll
            for (int e = 0; e < N_EXP; e++) acc[e] = rb[e];
            const float* xr = x + (size_t)tok * D_IN;
            for (int dd = 0; dd < D_IN; dd++) {
                float xv = xr[dd];
#pragma unroll
                for (int e = 0; e < N_EXP; e++) acc[e] += xv * s_rw[dd * N_EXP + e];
            }
            float m = acc[0];
#pragma unroll
            for (int e = 1; e < N_EXP; e++) m = fmaxf(m, acc[e]);
            float p[N_EXP], ssum = 0.f;
#pragma unroll
            for (int e = 0; e < N_EXP; e++) { p[e] = __expf(acc[e] - m); ssum += p[e]; }
            float inv = 1.f / ssum;
#pragma unroll
            for (int e = 0; e < N_EXP; e++) p[e] *= inv;
            int e0 = 0;
#pragma unroll
            for (int e = 1; e < N_EXP; e++) if (p[e] > p[e0]) e0 = e;
            int e1 = (e0 == 0) ? 1 : 0;
#pragma unroll
            for (int e = 0; e < N_EXP; e++) if (e != e0 && p[e] > p[e1]) e1 = e;
            float denom = 1.f / (p[e0] + p[e1]);
            tk_e[tok * 2] = e0; tk_e[tok * 2 + 1] = e1;
            tk_w[tok * 2] = p[e0] * denom; tk_w[tok * 2 + 1] = p[e1] * denom;
            atomicAdd(&s_cnt[e0], 1); atomicAdd(&s_cnt[e1], 1); atomicAdd(&s_t1[e0], 1);
#pragma unroll
            for (int e = 0; e < N_EXP; e++) atomicAdd(&s_ps[e], p[e]);
        }
        __syncthreads();
        if (tid < N_EXP) {
            atomicAdd(&counts[tid], s_cnt[tid]);
            atomicAdd(&top1cnt[tid], s_t1[tid]);
            atomicAdd(&probs_sum[tid], s_ps[tid]);
        }
    }
}

// ---- scatter: permutation via inline prefix of counts; block0 computes aux ----
__global__ __launch_bounds__(64) void scatter_kernel(
    const int* __restrict__ tk_e, const float* __restrict__ tk_w,
    const int* __restrict__ counts, int* cursors,
    int* rowTok, float* rowGate, int* pairPos,
    const int* __restrict__ top1cnt, const float* __restrict__ probs_sum, float* aux_out) {
    int tid = threadIdx.x;
    int tok = blockIdx.x * 64 + tid;
    int segOff[N_EXP];
    int off = 0;
#pragma unroll
    for (int e = 0; e < N_EXP; e++) { segOff[e] = off; off += counts[e]; }
#pragma unroll
    for (int k = 0; k < 2; k++) {
        int e = tk_e[tok * 2 + k];
        int pos = segOff[e] + atomicAdd(&cursors[e], 1);
        rowTok[pos] = tok;
        rowGate[pos] = tk_w[tok * 2 + k];
        pairPos[tok * 2 + k] = pos;
    }
    if (blockIdx.x == 0 && tid == 0) {
        float aux = 0.f;
#pragma unroll
        for (int e = 0; e < N_EXP; e++) aux += (float)top1cnt[e] * probs_sum[e];
        aux_out[0] = (float)N_EXP * aux / ((float)N_TOK * (float)N_TOK);
    }
}

// ---- gather ----
__global__ __launch_bounds__(192) void gather_kernel(
    const float* __restrict__ x, const int* __restrict__ rowTok, unsigned short* __restrict__ Xg) {
    int pos = blockIdx.x;
    int t = rowTok[pos];
    int i = threadIdx.x;
    float4 v = ((const float4*)(x + (size_t)t * D_IN))[i];
    unsigned long long pk = (unsigned long long)f2bf(v.x)
                          | ((unsigned long long)f2bf(v.y) << 16)
                          | ((unsigned long long)f2bf(v.z) << 32)
                          | ((unsigned long long)f2bf(v.w) << 48);
    *(unsigned long long*)(Xg + (size_t)pos * D_IN + (size_t)i * 4) = pk;
}

// ---- ffn1: H = silu(X@W1+b1) * (X@W2+b2), bf16 out (R8 structure) ----
__global__ __launch_bounds__(512) void ffn1_kernel(
    const unsigned short* __restrict__ Xg, const unsigned short* __restrict__ W1T,
    const unsigned short* __restrict__ W2T, const float* __restrict__ b1,
    const float* __restrict__ b2, unsigned short* __restrict__ Hbuf,
    const int* __restrict__ counts) {
    int u = xcd_swz(blockIdx.x, GRID1);
    int bx = u / (H_DIM / BN1);
    int by = u - bx * (H_DIM / BN1);
    int e, g0, vr;
    if (!tile_map(counts, bx, e, g0, vr)) return;
    int n0 = by * BN1;

    __shared__ __align__(16) unsigned short sA[BM * BK];
    __shared__ __align__(16) unsigned short sB1[BN1 * BK];
    __shared__ __align__(16) unsigned short sB2[BN1 * BK];

    int tid = threadIdx.x, lane = tid & 63, w = tid >> 6;
    int wm = w >> 2, wn = w & 3;
    int lr = lane & 15, lh = lane >> 4;

    f32x4 acc1[4][2], acc2[4][2];
#pragma unroll
    for (int a = 0; a < 4; a++)
#pragma unroll
        for (int b = 0; b < 2; b++) { acc1[a][b] = (f32x4)0.f; acc2[a][b] = (f32x4)0.f; }

    const unsigned short* W1e = W1T + (size_t)e * H_DIM * D_IN;
    const unsigned short* W2e = W2T + (size_t)e * H_DIM * D_IN;

    for (int kt = 0; kt < D_IN / BK; ++kt) {
        int kb = kt * BK;
#pragma unroll
        for (int ra = 0; ra < 2; ra++) {
            int o = ra * 8192 + tid * 16;
            int row = o >> 7;
            int c = ((o >> 4) & 7) ^ (row & 7);
            int gr = g0 + row; if (gr > NP - 1) gr = NP - 1;
            gload_lds16(Xg + (size_t)gr * D_IN + kb + c * 8, (char*)sA + o);
        }
#pragma unroll
        for (int rb2 = 0; rb2 < 2; rb2++) {
            int o = rb2 * 8192 + tid * 16;
            int row = o >> 7;
            int c = ((o >> 4) & 7) ^ (row & 7);
            size_t src = (size_t)(n0 + row) * D_IN + kb + c * 8;
            gload_lds16(W1e + src, (char*)sB1 + o);
            gload_lds16(W2e + src, (char*)sB2 + o);
        }
        asm volatile("s_waitcnt vmcnt(0)" ::: "memory");
        __syncthreads();
#pragma unroll
        for (int ks = 0; ks < 2; ++ks) {
            int sb = ks * 4 + lh;
            s16x8 av[4];
#pragma unroll
            for (int mf = 0; mf < 4; ++mf) {
                int r = wm * 64 + mf * 16 + lr;
                av[mf] = *(const s16x8*)&sA[r * 64 + ((sb ^ (r & 7)) << 3)];
            }
#pragma unroll
            for (int nf = 0; nf < 2; ++nf) {
                int n = wn * 32 + nf * 16 + lr;
                int off = n * 64 + ((sb ^ (n & 7)) << 3);
                s16x8 bv1 = *(const s16x8*)&sB1[off];
                s16x8 bv2 = *(const s16x8*)&sB2[off];
#pragma unroll
                for (int mf = 0; mf < 4; ++mf) {
                    acc1[mf][nf] = __builtin_amdgcn_mfma_f32_16x16x32_bf16(av[mf], bv1, acc1[mf][nf], 0, 0, 0);
                    acc2[mf][nf] = __builtin_amdgcn_mfma_f32_16x16x32_bf16(av[mf], bv2, acc2[mf][nf], 0, 0, 0);
                }
            }
        }
        __syncthreads();
    }
#pragma unroll
    for (int mf = 0; mf < 4; ++mf) {
        int rbase = wm * 64 + mf * 16 + lh * 4;
#pragma unroll
        for (int nf = 0; nf < 2; ++nf) {
            int n = n0 + wn * 32 + nf * 16 + lr;
            float bb1 = b1[e * H_DIM + n], bb2 = b2[e * H_DIM + n];
#pragma unroll
            for (int j = 0; j < 4; ++j) {
                int r = rbase + j;
                if (r < vr) {
                    float x1 = acc1[mf][nf][j] + bb1;
                    float x2 = acc2[mf][nf][j] + bb2;
                    float h = x1 / (1.f + __expf(-x1)) * x2;
                    Hbuf[(size_t)(g0 + r) * H_DIM + n] = f2bf(h);
                }
            }
        }
    }
}

// ---- ffn2: Y = gate * (H@W3 + b3), f32 out (R8 structure) ----
__global__ __launch_bounds__(256) void ffn2_kernel(
    const unsigned short* __restrict__ Hbuf, const unsigned short* __restrict__ W3T,
    const float* __restrict__ b3, const float* __restrict__ rowGate,
    float* __restrict__ Ybuf, const int* __restrict__ counts) {
    int u = xcd_swz(blockIdx.x, GRID2);
    int bx = u / (D_IN / BN2);
    int by = u - bx * (D_IN / BN2);
    int e, g0, vr;
    if (!tile_map(counts, bx, e, g0, vr)) return;
    int n0 = by * BN2;

    __shared__ __align__(16) unsigned short sA[2][BM * BK];
    __shared__ __align__(16) unsigned short sB[2][BN2 * BK];

    int tid = threadIdx.x, lane = tid & 63, w = tid >> 6;
    int wm = w >> 1, wn = w & 1;
    int lr = lane & 15, lh = lane >> 4;

    f32x4 acc[4][4];
#pragma unroll
    for (int a = 0; a < 4; a++)
#pragma unroll
        for (int b = 0; b < 4; b++) acc[a][b] = (f32x4)0.f;

    const unsigned short* W3e = W3T + (size_t)e * D_IN * H_DIM;

    auto stage = [&](int buf, int kt) {
        int kb = kt * BK;
#pragma unroll
        for (int ca = 0; ca < 4; ca++) {
            int o = ca * 4096 + tid * 16;
            int row = o >> 7;
            int c = ((o >> 4) & 7) ^ (row & 7);
            int gr = g0 + row; if (gr > NP - 1) gr = NP - 1;
            gload_lds16(Hbuf + (size_t)gr * H_DIM + kb + c * 8, (char*)&sA[buf][0] + o);
        }
#pragma unroll
        for (int cb = 0; cb < 4; cb++) {
            int o = cb * 4096 + tid * 16;
            int row = o >> 7;
            int c = ((o >> 4) & 7) ^ (row & 7);
            gload_lds16(W3e + (size_t)(n0 + row) * H_DIM + kb + c * 8, (char*)&sB[buf][0] + o);
        }
    };

    const int NKT = H_DIM / BK;
    stage(0, 0);
    stage(1, 1);
    __builtin_amdgcn_sched_barrier(0);
#pragma unroll 1
    for (int kt = 0; kt < NKT; ++kt) {
        if (kt < NKT - 1) { asm volatile("s_waitcnt vmcnt(8)" ::: "memory"); }
        else              { asm volatile("s_waitcnt vmcnt(0)" ::: "memory"); }
        __builtin_amdgcn_s_barrier();
        __builtin_amdgcn_sched_barrier(0);
        int cur = kt & 1;
#pragma unroll
        for (int ks = 0; ks < 2; ++ks) {
            int sb = ks * 4 + lh;
            s16x8 av[4], bv[4];
#pragma unroll
            for (int mf = 0; mf < 4; ++mf) {
                int r = wm * 64 + mf * 16 + lr;
                av[mf] = *(const s16x8*)&sA[cur][r * 64 + ((sb ^ (r & 7)) << 3)];
            }
#pragma unroll
            for (int nf = 0; nf < 4; ++nf) {
                int n = wn * 64 + nf * 16 + lr;
                bv[nf] = *(const s16x8*)&sB[cur][n * 64 + ((sb ^ (n & 7)) << 3)];
            }
#pragma unroll
            for (int nf = 0; nf < 4; ++nf)
#pragma unroll
                for (int mf = 0; mf < 4; ++mf)
                    acc[mf][nf] = __builtin_amdgcn_mfma_f32_16x16x32_bf16(av[mf], bv[nf], acc[mf][nf], 0, 0, 0);
        }
        __builtin_amdgcn_sched_barrier(0);
        __builtin_amdgcn_s_barrier();
        if (kt + 2 < NKT) { stage(cur, kt + 2); __builtin_amdgcn_sched_barrier(0); }
    }
#pragma unroll
    for (int mf = 0; mf < 4; ++mf) {
        int rbase = wm * 64 + mf * 16 + lh * 4;
#pragma unroll
        for (int nf = 0; nf < 4; ++nf) {
            int n = n0 + wn * 64 + nf * 16 + lr;
            float bb = b3[e * D_IN + n];
#pragma unroll
            for (int j = 0; j < 4; ++j) {
                int r = rbase + j;
                if (r < vr) {
                    float g = rowGate[g0 + r];
                    Ybuf[(size_t)(g0 + r) * D_IN + n] = g * (acc[mf][nf][j] + bb);
                }
            }
        }
    }
}

// ---- combine ----
__global__ __launch_bounds__(192) void combine_kernel(
    const float* __restrict__ Ybuf, const int* __restrict__ pairPos, float* __restrict__ out) {
    int t = blockIdx.x, i = threadIdx.x;
    int p0 = pairPos[t * 2], p1 = pairPos[t * 2 + 1];
    float4 a = ((const float4*)(Ybuf + (size_t)p0 * D_IN))[i];
    float4 b = ((const float4*)(Ybuf + (size_t)p1 * D_IN))[i];
    float4 r; r.x = a.x + b.x; r.y = a.y + b.y; r.z = a.z + b.z; r.w = a.w + b.w;
    ((float4*)(out + (size_t)t * D_IN))[i] = r;
}

extern "C" void kernel_launch(void* const* d_in, const int* in_sizes, int n_in,
                              void* d_out, int out_size, void* d_ws, size_t ws_size,
                              hipStream_t stream) {
    const float* x  = (const float*)d_in[0];
    const float* rw = (const float*)d_in[1];
    const float* rb = (const float*)d_in[2];
    const float* w1 = (const float*)d_in[3];
    const float* b1 = (const float*)d_in[4];
    const float* w2 = (const float*)d_in[5];
    const float* b2 = (const float*)d_in[6];
    const float* w3 = (const float*)d_in[7];
    const float* b3 = (const float*)d_in[8];
    float* out = (float*)d_out;

    char* ws = (char*)d_ws;
    const size_t sW = (size_t)N_EXP * H_DIM * D_IN * 2;
    unsigned short* W1T = (unsigned short*)(ws);
    unsigned short* W2T = (unsigned short*)(ws + sW);
    unsigned short* W3T = (unsigned short*)(ws + 2 * sW);
    unsigned short* Xg  = (unsigned short*)(ws + 3 * sW);
    unsigned short* Hb  = (unsigned short*)(ws + 3 * sW + (size_t)NP * D_IN * 2);
    float* Yb = (float*)(ws + 3 * sW + (size_t)NP * D_IN * 2 + (size_t)NP * H_DIM * 2);
    char* meta = (char*)(Yb + (size_t)NP * D_IN);
    int*   counts  = (int*)(meta + 0);
    int*   top1    = (int*)(meta + 32);
    float* psum    = (float*)(meta + 64);
    int*   cursors = (int*)(meta + 96);
    int*   tk_e    = (int*)(meta + 1024);
    float* tk_w    = (float*)(meta + 1024 + 32768);
    int*   rowTok  = (int*)(meta + 1024 + 65536);
    float* rowGate = (float*)(meta + 1024 + 98304);
    int*   pairPos = (int*)(meta + 1024 + 131072);
    size_t need = (size_t)(meta - ws) + 1024 + 163840;
    if (ws_size < need) return;

    hipMemsetAsync(meta, 0, 128, stream);
    prep_kernel<<<NT_BLKS + 64, 256, 0, stream>>>(
        w1, w2, w3, W1T, W2T, W3T, x, rw, rb, counts, top1, psum, tk_e, tk_w);
    scatter_kernel<<<N_TOK / 64, 64, 0, stream>>>(
        tk_e, tk_w, counts, cursors, rowTok, rowGate, pairPos,
        top1, psum, out + (size_t)N_TOK * D_IN);
    gather_kernel<<<NP, 192, 0, stream>>>(x, rowTok, Xg);
    ffn1_kernel<<<GRID1, 512, 0, stream>>>(Xg, W1T, W2T, b1, b2, Hb, counts);
    ffn2_kernel<<<GRID2, 256, 0, stream>>>(Hb, W3T, b3, rowGate, Yb, counts);
    combine_kernel<<<N_TOK, 192, 0, stream>>>(Yb, pairPos, out);
}